// Round 3
// baseline (75.070 us; speedup 1.0000x reference)
//
#include <hip/hip_runtime.h>
#include <cstdint>

// CovNet BNN: out = clip(x @ sign(W1)^T + b1, ±1) @ W2^T + b2
// B=8192, IN=784, HID=4096, OUT=10.
// R3: deep pipeline. M-interleaved wave ownership (row = mi*32 + wm*16) so
// phase P1 reads only A-half0 and P2 only A-half1 for ALL waves. B 3-ring,
// A-half 2-ring => LDS 160 KiB. Counted vmcnt with tail-peeled constants:
//   issue order/tile t: P1: Ah1(t+1)[2] B(t+2)[4] | P2: Ah0(t+2)[2]
//   W2(t) before P2 reads Ah1(t): steady vmcnt(12); t=NKT-2: 8; t=NKT-1: 0
//   W1(t+1) before P1 reads Ah0(t+1),B(t+1): steady vmcnt(8); t=NKT-2: 2
// Fused GEMM2 epilogue -> partials -> reduce, unchanged from R2 (passed).

#define BATCH 8192
#define IN_F  784
#define HID   4096
#define OUT_F 10
#define KP    832     // padded K = 13*64
#define NKT   13
#define BM    256
#define BN    256
#define BK    64
#define NCT   (HID / BN)   // 16 col tiles
#define HCS   264          // epilogue hc row stride (f16)

typedef unsigned short u16;
typedef __attribute__((ext_vector_type(8))) _Float16 f16x8;
typedef __attribute__((ext_vector_type(4))) float    f32x4;

#define BARRIER() do { asm volatile("" ::: "memory"); \
                       __builtin_amdgcn_s_barrier();  \
                       asm volatile("" ::: "memory"); } while (0)
#define WAITV(n)  asm volatile("s_waitcnt vmcnt(" #n ")" ::: "memory")

__device__ __forceinline__ u16 f2h(float f) {
  union { _Float16 h; u16 u; } c;
  c.h = (_Float16)f;   // RNE
  return c.u;
}

__device__ __forceinline__ void gl_lds16(const void* g, void* l) {
  __builtin_amdgcn_global_load_lds(
      (const __attribute__((address_space(1))) uint32_t*)g,
      (__attribute__((address_space(3))) uint32_t*)l, 16, 0, 0);
}

// ---------------- prep: x -> f16 (padded), W1 -> sign f16 (padded), W2 -> f16 [16][4096]
__global__ void prep_kernel(const float* __restrict__ x, const float* __restrict__ W1,
                            const float* __restrict__ W2,
                            u16* __restrict__ xh, u16* __restrict__ wh,
                            u16* __restrict__ w2h) {
  const int stride = gridDim.x * blockDim.x;
  const int gid = blockIdx.x * blockDim.x + threadIdx.x;
  for (int i = gid; i < BATCH * KP; i += stride) {
    int b = i / KP, k = i - b * KP;
    float v = (k < IN_F) ? x[b * IN_F + k] : 0.f;
    xh[i] = f2h(v);
  }
  for (int i = gid; i < HID * KP; i += stride) {
    int h = i / KP, k = i - h * KP;
    float v = 0.f;
    if (k < IN_F) {
      float w = W1[h * IN_F + k];
      v = (w > 0.f) ? 1.f : ((w < 0.f) ? -1.f : 0.f);
    }
    wh[i] = f2h(v);
  }
  for (int i = gid; i < 16 * HID; i += stride) {
    int o = i >> 12, k = i & (HID - 1);
    w2h[i] = (o < OUT_F) ? f2h(W2[o * HID + k]) : (u16)0;
  }
}

// ---------------- main fused GEMM (256x256, 8 waves, deep counted-vmcnt pipeline)
__global__ void __launch_bounds__(512, 2) gemm_kernel(
    const u16* __restrict__ xh, const u16* __restrict__ wh,
    const u16* __restrict__ w2h, const float* __restrict__ b1,
    float* __restrict__ part) {
  __shared__ union {
    struct {
      u16 A0[2][128 * BK];   // A rows   0..127, 2-ring by tile parity (32 KiB)
      u16 A1[2][128 * BK];   // A rows 128..255, 2-ring                (32 KiB)
      u16 B[3][BN * BK];     // B tile, 3-ring                         (96 KiB)
    } m;                                                       // 160 KiB
    struct { u16 hc[128 * HCS]; u16 w2[16 * 256]; } e;         // ~74 KiB epilogue
  } sm;

  const int t   = threadIdx.x;
  const int ct  = blockIdx.x;   // col tile (HID), 0..15
  const int br  = blockIdx.y;   // row tile (BATCH), 0..31
  const int w   = t >> 6;       // wave 0..7
  const int l   = t & 63;
  const int wm  = w >> 2;       // 0..1  (M interleave: row = mi*32 + wm*16)
  const int wn  = w & 3;        // 0..3  (N quarter: col = wn*64 + ni*16)
  const int g   = l >> 4;
  const int r16 = l & 15;
  const int swz = (r16 & 7) << 3;   // f16-unit XOR (16B-slot granule) for frag reads

  // staging: thread t covers 16B; per 64-row chunk: row = t>>3, log. slot = (t&7)^(row&7).
  // LDS dest linear; swizzle applied by permuting the GLOBAL source slot (rule #21).
  const int  srow  = t >> 3;                 // 0..63 within chunk
  const int  sslot = (t & 7) ^ (srow & 7);
  const u16* gA = xh + (size_t)(br * BM) * KP + sslot * 8;
  const u16* gB = wh + (size_t)(ct * BN) * KP + sslot * 8;

  auto stA0 = [&](int tile, int c) {   // c 0..1 -> tile rows c*64..c*64+63
    gl_lds16(gA + (size_t)(c * 64 + srow) * KP + tile * BK,
             &sm.m.A0[tile & 1][c * 4096 + t * 8]);
  };
  auto stA1 = [&](int tile, int c) {   // tile rows 128 + c*64 ...
    gl_lds16(gA + (size_t)(128 + c * 64 + srow) * KP + tile * BK,
             &sm.m.A1[tile & 1][c * 4096 + t * 8]);
  };
  auto stB = [&](int tile, int c, int slot) {   // c 0..3
    gl_lds16(gB + (size_t)(c * 64 + srow) * KP + tile * BK,
             &sm.m.B[slot][c * 4096 + t * 8]);
  };
  auto rdA0 = [&](int s, int mi, int kk) -> f16x8 {   // mi 0..3
    return *(const f16x8*)&sm.m.A0[s][(mi * 32 + wm * 16 + r16) * BK + ((kk * 32 + g * 8) ^ swz)];
  };
  auto rdA1 = [&](int s, int mi, int kk) -> f16x8 {   // mi 0..3 (global mi+4)
    return *(const f16x8*)&sm.m.A1[s][(mi * 32 + wm * 16 + r16) * BK + ((kk * 32 + g * 8) ^ swz)];
  };
  auto rdB = [&](int s, int ni, int kk) -> f16x8 {
    return *(const f16x8*)&sm.m.B[s][(wn * 64 + ni * 16 + r16) * BK + ((kk * 32 + g * 8) ^ swz)];
  };

  f32x4 acc[8][4] = {};

  // ---- prologue: issue order must match steady-state ledger ----
  stB(0, 0, 0); stB(0, 1, 0); stB(0, 2, 0); stB(0, 3, 0);   // B(0)   [4]
  stA0(0, 0); stA0(0, 1);                                   // Ah0(0) [2]
  stA1(0, 0); stA1(0, 1);                                   // Ah1(0) [2]
  stB(1, 0, 1); stB(1, 1, 1); stB(1, 2, 1); stB(1, 3, 1);   // B(1)   [4]
  stA0(1, 0); stA0(1, 1);                                   // Ah0(1) [2]
  WAITV(8);    // drain B(0), Ah0(0); leaves Ah1(0)+B(1)+Ah0(1) = 8
  BARRIER();

  int bs = 0;   // tt % 3
  for (int tt = 0; tt < NKT; ++tt) {
    const int sa  = tt & 1;
    int bs2 = bs + 2; if (bs2 >= 3) bs2 -= 3;   // (tt+2) % 3

    // ---- P1: compute mi 0-3 (A-half0) ----
    if (tt + 1 < NKT) { stA1(tt + 1, 0); stA1(tt + 1, 1); }          // [2]
    if (tt + 2 < NKT) { stB(tt + 2, 0, bs2); stB(tt + 2, 1, bs2);
                        stB(tt + 2, 2, bs2); stB(tt + 2, 3, bs2); }  // [4]
    f16x8 bf[4][2], af[4][2];
#pragma unroll
    for (int ni = 0; ni < 4; ++ni)
#pragma unroll
      for (int kk = 0; kk < 2; ++kk) bf[ni][kk] = rdB(bs, ni, kk);
#pragma unroll
    for (int mi = 0; mi < 4; ++mi)
#pragma unroll
      for (int kk = 0; kk < 2; ++kk) af[mi][kk] = rdA0(sa, mi, kk);
    __builtin_amdgcn_s_setprio(1);
#pragma unroll
    for (int kk = 0; kk < 2; ++kk)
#pragma unroll
      for (int mi = 0; mi < 4; ++mi)
#pragma unroll
        for (int ni = 0; ni < 4; ++ni)
          acc[mi][ni] = __builtin_amdgcn_mfma_f32_16x16x32_f16(af[mi][kk], bf[ni][kk], acc[mi][ni], 0, 0, 0);
    __builtin_amdgcn_s_setprio(0);
    // W2(tt): drain Ah1(tt) before P2 reads it
    if (tt < NKT - 2)       { WAITV(12); }
    else if (tt == NKT - 2) { WAITV(8); }
    else                    { WAITV(0); }
    BARRIER();   // Ah0(tt) reads done before staging Ah0(tt+2) into same slot

    // ---- P2: compute mi 4-7 (A-half1) ----
    if (tt + 2 < NKT) { stA0(tt + 2, 0); stA0(tt + 2, 1); }          // [2]
#pragma unroll
    for (int mi = 0; mi < 4; ++mi)
#pragma unroll
      for (int kk = 0; kk < 2; ++kk) af[mi][kk] = rdA1(sa, mi, kk);
    __builtin_amdgcn_s_setprio(1);
#pragma unroll
    for (int kk = 0; kk < 2; ++kk)
#pragma unroll
      for (int mi = 0; mi < 4; ++mi)
#pragma unroll
        for (int ni = 0; ni < 4; ++ni)
          acc[mi + 4][ni] = __builtin_amdgcn_mfma_f32_16x16x32_f16(af[mi][kk], bf[ni][kk], acc[mi + 4][ni], 0, 0, 0);
    __builtin_amdgcn_s_setprio(0);
    // W1(tt+1): drain Ah0(tt+1), B(tt+1) before next P1 reads them
    if (tt < NKT - 2)       { WAITV(8); }
    else if (tt == NKT - 2) { WAITV(2); }
    BARRIER();   // Ah1(tt)/B(tt) reads done before next-tile staging reuses slots

    bs = bs + 1; if (bs == 3) bs = 0;
  }

  // ---- epilogue: h = clip(acc + b1), fused GEMM2 through LDS ----
  // (all main-loop loads drained: W2(NKT-1) = vmcnt(0) + barrier)
  {
    int row = t >> 5, sp = t & 31;
    int ls = (sp & 24) | ((sp ^ row) & 7);   // swizzled logical slot
    gl_lds16(w2h + (size_t)row * HID + ct * BN + ls * 8, &sm.e.w2[t * 8]);
  }
  float b1v[4];
#pragma unroll
  for (int ni = 0; ni < 4; ++ni) b1v[ni] = b1[ct * BN + wn * 64 + ni * 16 + r16];

  float* partBase = part + ((size_t)ct * BATCH + br * BM) * 16;

#pragma unroll
  for (int p = 0; p < 2; ++p) {
    if (p == 1) BARRIER();               // p=0 hc reads done before overwrite
    // pass p writes A-half p rows: global row = (p*4+mi)*32 + wm*16 + g*4 + r
    //   local hc row = mi*32 + wm*16 + g*4 + r  (mi 0..3)
#pragma unroll
    for (int mi = 0; mi < 4; ++mi)
#pragma unroll
      for (int ni = 0; ni < 4; ++ni)
#pragma unroll
        for (int r = 0; r < 4; ++r) {
          float v = acc[p * 4 + mi][ni][r] + b1v[ni];
          v = fminf(fmaxf(v, -1.f), 1.f);
          sm.e.hc[(mi * 32 + wm * 16 + g * 4 + r) * HCS + wn * 64 + ni * 16 + r16] = f2h(v);
        }
    if (p == 0) { WAITV(0); }            // w2 landed
    BARRIER();
    f32x4 acc2 = {};
#pragma unroll
    for (int kk = 0; kk < 8; ++kk) {
      f16x8 a2 = *(const f16x8*)&sm.e.hc[(w * 16 + r16) * HCS + kk * 32 + g * 8];
      int s   = kk * 4 + g;
      int sp2 = (s & 24) | ((s ^ r16) & 7);
      f16x8 b2f = *(const f16x8*)&sm.e.w2[r16 * 256 + sp2 * 8];
      acc2 = __builtin_amdgcn_mfma_f32_16x16x32_f16(a2, b2f, acc2, 0, 0, 0);
    }
#pragma unroll
    for (int r = 0; r < 4; ++r)
      partBase[(size_t)(p * 128 + w * 16 + g * 4 + r) * 16 + r16] = acc2[r];
  }
}

// ---------------- reduce partials over 16 col tiles + b2
__global__ void reduce_kernel(const float* __restrict__ part, const float* __restrict__ b2,
                              float* __restrict__ out) {
  int i = blockIdx.x * blockDim.x + threadIdx.x;
  if (i >= BATCH * OUT_F) return;
  int b = i / OUT_F, o = i - b * OUT_F;
  float acc = b2[o];
#pragma unroll
  for (int c = 0; c < NCT; ++c)
    acc += part[((size_t)c * BATCH + b) * 16 + o];
  out[i] = acc;
}

extern "C" void kernel_launch(void* const* d_in, const int* in_sizes, int n_in,
                              void* d_out, int out_size, void* d_ws, size_t ws_size,
                              hipStream_t stream) {
  const float* x  = (const float*)d_in[0];
  const float* W1 = (const float*)d_in[1];
  const float* b1 = (const float*)d_in[2];
  const float* W2 = (const float*)d_in[3];
  const float* b2 = (const float*)d_in[4];
  float* out = (float*)d_out;

  // ws layout (~29 MB):
  //   xh  : 8192*832 f16 = 13.6 MB
  //   wh  : 4096*832 f16 =  6.8 MB
  //   w2h : 16*4096  f16 =  0.13 MB
  //   part: 16*8192*16 f32 = 8.4 MB
  u16* xh  = (u16*)d_ws;
  u16* wh  = xh + (size_t)BATCH * KP;
  u16* w2h = wh + (size_t)HID * KP;
  float* part = (float*)(w2h + 16 * HID);

  hipLaunchKernelGGL(prep_kernel, dim3(1024), dim3(256), 0, stream, x, W1, W2, xh, wh, w2h);
  hipLaunchKernelGGL(gemm_kernel, dim3(NCT, BATCH / BM), dim3(512), 0, stream,
                     xh, wh, w2h, b1, part);
  hipLaunchKernelGGL(reduce_kernel, dim3((BATCH * OUT_F + 255) / 256), dim3(256), 0, stream,
                     part, b2, out);
}

// Round 4
// 68.057 us; speedup vs baseline: 1.1030x; 1.1030x over previous
//
#include <hip/hip_runtime.h>
#include <cstdint>

// CovNet BNN: out = clip(x @ sign(W1)^T + b1, ±1) @ W2^T + b2
// B=8192, IN=784, HID=4096, OUT=10.
// R4: m201-style fine-grained schedule. 4 phases per K-tile (one C-quadrant
// each): {12 ds_read; stage 1 half-tile; counted vmcnt; barrier; 16 MFMA}.
// A rows M-interleaved (mi*32+wm*16), B cols N-interleaved (ni*64+wn*16) so
// quadrant (mh,nh) reads only A-half mh + B-half nh. Gray walk (00,10,11,01).
// Stage ledger (all stages of tile t+1 go to buf p^1 -> race-free; barrier2
// only at q3 for the cross-tile read/write hazard):
//   entering q0(t): outstanding [Ah1(t),Bh1(t)]
//   q0: +Ah0(t+1) ->6, vmcnt(4) clears Ah1(t)   (needed q1)
//   q1: +Bh0(t+1) ->6, vmcnt(4) clears Bh1(t)   (needed q2)
//   q2: +Ah1(t+1) ->6, no wait
//   q3: +Bh1(t+1) ->8, vmcnt(4) clears Ah0,Bh0(t+1) (needed q0(t+1))
//   tile 12 (no stages): q0 vmcnt(2), q1 vmcnt(0)
// Fused GEMM2 epilogue -> partials -> reduce (R2/R3-proven, col remap only).

#define BATCH 8192
#define IN_F  784
#define HID   4096
#define OUT_F 10
#define KP    832     // padded K = 13*64
#define NKT   13
#define BM    256
#define BN    256
#define BK    64
#define NCT   (HID / BN)   // 16 col tiles
#define HCS   264          // epilogue hc row stride (f16)

typedef unsigned short u16;
typedef __attribute__((ext_vector_type(4))) unsigned short u16x4;
typedef __attribute__((ext_vector_type(8))) _Float16 f16x8;
typedef __attribute__((ext_vector_type(4))) float    f32x4;

#define BARRIER() do { asm volatile("" ::: "memory"); \
                       __builtin_amdgcn_s_barrier();  \
                       asm volatile("" ::: "memory"); } while (0)
#define WAITV(n)  asm volatile("s_waitcnt vmcnt(" #n ")" ::: "memory")

__device__ __forceinline__ u16 f2h(float f) {
  union { _Float16 h; u16 u; } c;
  c.h = (_Float16)f;   // RNE
  return c.u;
}

__device__ __forceinline__ void gl_lds16(const void* g, void* l) {
  __builtin_amdgcn_global_load_lds(
      (const __attribute__((address_space(1))) uint32_t*)g,
      (__attribute__((address_space(3))) uint32_t*)l, 16, 0, 0);
}

// ---------------- prep: x -> f16 (padded), W1 -> sign f16 (padded), W2 -> [16][4096]
__global__ void prep_kernel(const float* __restrict__ x, const float* __restrict__ W1,
                            const float* __restrict__ W2,
                            u16* __restrict__ xh, u16* __restrict__ wh,
                            u16* __restrict__ w2h) {
  const int stride = gridDim.x * blockDim.x;
  const int gid = blockIdx.x * blockDim.x + threadIdx.x;
  const int KP4 = KP / 4;    // 208
  const int IN4 = IN_F / 4;  // 196
  const float4* x4 = (const float4*)x;
  const float4* w4 = (const float4*)W1;
  for (int i = gid; i < BATCH * KP4; i += stride) {
    int b = i / KP4, k = i - b * KP4;
    u16x4 o = {0, 0, 0, 0};
    if (k < IN4) {
      float4 v = x4[(size_t)b * IN4 + k];
      o[0] = f2h(v.x); o[1] = f2h(v.y); o[2] = f2h(v.z); o[3] = f2h(v.w);
    }
    *(u16x4*)&xh[(size_t)b * KP + k * 4] = o;
  }
  for (int i = gid; i < HID * KP4; i += stride) {
    int h = i / KP4, k = i - h * KP4;
    u16x4 o = {0, 0, 0, 0};
    if (k < IN4) {
      float4 v = w4[(size_t)h * IN4 + k];
      o[0] = v.x > 0.f ? 0x3C00 : (v.x < 0.f ? 0xBC00 : 0);
      o[1] = v.y > 0.f ? 0x3C00 : (v.y < 0.f ? 0xBC00 : 0);
      o[2] = v.z > 0.f ? 0x3C00 : (v.z < 0.f ? 0xBC00 : 0);
      o[3] = v.w > 0.f ? 0x3C00 : (v.w < 0.f ? 0xBC00 : 0);
    }
    *(u16x4*)&wh[(size_t)h * KP + k * 4] = o;
  }
  for (int i = gid; i < 16 * HID; i += stride) {
    int o = i >> 12, k = i & (HID - 1);
    w2h[i] = (o < OUT_F) ? f2h(W2[o * HID + k]) : (u16)0;
  }
}

// ---------------- main fused GEMM (256x256, 8 waves, 4-phase fine interleave)
__global__ void __launch_bounds__(512, 2) gemm_kernel(
    const u16* __restrict__ xh, const u16* __restrict__ wh,
    const u16* __restrict__ w2h, const float* __restrict__ b1,
    float* __restrict__ part) {
  __shared__ union {
    struct { u16 A[2][2][128 * BK]; u16 B[2][2][128 * BK]; } m;  // 128 KiB
    struct { u16 hc[128 * HCS]; u16 w2[16 * 256]; } e;           // ~74 KiB
  } sm;

  const int t   = threadIdx.x;
  const int ct  = blockIdx.x;   // col tile (HID), 0..15
  const int br  = blockIdx.y;   // row tile (BATCH), 0..31
  const int w   = t >> 6;       // wave 0..7
  const int l   = t & 63;
  const int wm  = w >> 2;       // row = mi*32 + wm*16  (M interleave)
  const int wn  = w & 3;        // col = ni*64 + wn*16  (N interleave)
  const int g   = l >> 4;
  const int r16 = l & 15;
  const int swz = (r16 & 7) << 3;   // f16-unit XOR (16B-slot granule)

  // staging: thread t covers 16B; per 64-row chunk: row = t>>3, slot swizzled
  // on the GLOBAL source side (rule #21); LDS dest linear.
  const int  srow  = t >> 3;
  const int  sslot = (t & 7) ^ (srow & 7);
  const u16* gA = xh + (size_t)(br * BM) * KP + sslot * 8;
  const u16* gB = wh + (size_t)(ct * BN) * KP + sslot * 8;

  auto stA = [&](int tile, int h) {   // A-half h = tile rows h*128..h*128+127
#pragma unroll
    for (int c = 0; c < 2; ++c)
      gl_lds16(gA + (size_t)(h * 128 + c * 64 + srow) * KP + tile * BK,
               &sm.m.A[tile & 1][h][c * 4096 + t * 8]);
  };
  auto stB = [&](int tile, int h) {   // B-half h = tile cols h*128..h*128+127
#pragma unroll
    for (int c = 0; c < 2; ++c)
      gl_lds16(gB + (size_t)(h * 128 + c * 64 + srow) * KP + tile * BK,
               &sm.m.B[tile & 1][h][c * 4096 + t * 8]);
  };
  auto rdA = [&](int p, int h, int mi, int kk) -> f16x8 {   // mi 0..3 within half
    return *(const f16x8*)&sm.m.A[p][h][(mi * 32 + wm * 16 + r16) * BK + ((kk * 32 + g * 8) ^ swz)];
  };
  auto rdB = [&](int p, int h, int ni, int kk) -> f16x8 {   // ni 0..1 within half
    return *(const f16x8*)&sm.m.B[p][h][(ni * 64 + wn * 16 + r16) * BK + ((kk * 32 + g * 8) ^ swz)];
  };

  f32x4 acc[8][4] = {};

  // prologue: order matters for the vmcnt ledger (Ah0,Bh0 oldest)
  stA(0, 0); stB(0, 0); stA(0, 1); stB(0, 1);
  WAITV(4);   // clears Ah0(0),Bh0(0); leaves [Ah1(0),Bh1(0)]
  BARRIER();

  for (int tt = 0; tt < NKT; ++tt) {
    const int  p    = tt & 1;
    const bool more = (tt + 1 < NKT);
#pragma unroll
    for (int q = 0; q < 4; ++q) {
      const int mh = (q == 1 || q == 2) ? 1 : 0;   // Gray walk
      const int nh = q >> 1;
      f16x8 af[4][2], bf[2][2];
#pragma unroll
      for (int ni = 0; ni < 2; ++ni)
#pragma unroll
        for (int kk = 0; kk < 2; ++kk) bf[ni][kk] = rdB(p, nh, ni, kk);
#pragma unroll
      for (int mi = 0; mi < 4; ++mi)
#pragma unroll
        for (int kk = 0; kk < 2; ++kk) af[mi][kk] = rdA(p, mh, mi, kk);
      if (more) {
        if      (q == 0) stA(tt + 1, 0);
        else if (q == 1) stB(tt + 1, 0);
        else if (q == 2) stA(tt + 1, 1);
        else             stB(tt + 1, 1);
        if (q != 2) WAITV(4);
      } else {
        if      (q == 0) WAITV(2);
        else if (q == 1) WAITV(0);
      }
      BARRIER();
      __builtin_amdgcn_s_setprio(1);
#pragma unroll
      for (int kk = 0; kk < 2; ++kk)
#pragma unroll
        for (int mi = 0; mi < 4; ++mi)
#pragma unroll
          for (int ni = 0; ni < 2; ++ni)
            acc[mh * 4 + mi][nh * 2 + ni] = __builtin_amdgcn_mfma_f32_16x16x32_f16(
                af[mi][kk], bf[ni][kk], acc[mh * 4 + mi][nh * 2 + ni], 0, 0, 0);
      __builtin_amdgcn_s_setprio(0);
      if (q == 3) BARRIER();   // cross-tile: buf p reads done before q0(t+1) stage
    }
  }

  // ---- epilogue: h = clip(acc + b1), fused GEMM2 through LDS ----
  // (all main-loop vmem drained: tile 12 q1 waited vmcnt(0))
  {
    int row = t >> 5, sp = t & 31;
    int ls = (sp & 24) | ((sp ^ row) & 7);   // swizzled logical slot
    gl_lds16(w2h + (size_t)row * HID + ct * BN + ls * 8, &sm.e.w2[t * 8]);
  }
  float b1v[4];
#pragma unroll
  for (int ni = 0; ni < 4; ++ni) b1v[ni] = b1[ct * BN + ni * 64 + wn * 16 + r16];

  float* partBase = part + ((size_t)ct * BATCH + br * BM) * 16;

#pragma unroll
  for (int p = 0; p < 2; ++p) {
    if (p == 1) BARRIER();               // p=0 hc reads done before overwrite
    // pass p writes A-half p rows: local row = mi*32 + wm*16 + g*4 + r
#pragma unroll
    for (int mi = 0; mi < 4; ++mi)
#pragma unroll
      for (int ni = 0; ni < 4; ++ni)
#pragma unroll
        for (int r = 0; r < 4; ++r) {
          float v = acc[p * 4 + mi][ni][r] + b1v[ni];
          v = fminf(fmaxf(v, -1.f), 1.f);
          sm.e.hc[(mi * 32 + wm * 16 + g * 4 + r) * HCS + ni * 64 + wn * 16 + r16] = f2h(v);
        }
    if (p == 0) { WAITV(0); }            // w2 landed
    BARRIER();
    f32x4 acc2 = {};
#pragma unroll
    for (int kk = 0; kk < 8; ++kk) {
      f16x8 a2 = *(const f16x8*)&sm.e.hc[(w * 16 + r16) * HCS + kk * 32 + g * 8];
      int s   = kk * 4 + g;
      int sp2 = (s & 24) | ((s ^ r16) & 7);
      f16x8 b2f = *(const f16x8*)&sm.e.w2[r16 * 256 + sp2 * 8];
      acc2 = __builtin_amdgcn_mfma_f32_16x16x32_f16(a2, b2f, acc2, 0, 0, 0);
    }
#pragma unroll
    for (int r = 0; r < 4; ++r)
      partBase[(size_t)(p * 128 + w * 16 + g * 4 + r) * 16 + r16] = acc2[r];
  }
}

// ---------------- reduce partials over 16 col tiles + b2
__global__ void reduce_kernel(const float* __restrict__ part, const float* __restrict__ b2,
                              float* __restrict__ out) {
  int i = blockIdx.x * blockDim.x + threadIdx.x;
  if (i >= BATCH * OUT_F) return;
  int b = i / OUT_F, o = i - b * OUT_F;
  float acc = b2[o];
#pragma unroll
  for (int c = 0; c < NCT; ++c)
    acc += part[((size_t)c * BATCH + b) * 16 + o];
  out[i] = acc;
}

extern "C" void kernel_launch(void* const* d_in, const int* in_sizes, int n_in,
                              void* d_out, int out_size, void* d_ws, size_t ws_size,
                              hipStream_t stream) {
  const float* x  = (const float*)d_in[0];
  const float* W1 = (const float*)d_in[1];
  const float* b1 = (const float*)d_in[2];
  const float* W2 = (const float*)d_in[3];
  const float* b2 = (const float*)d_in[4];
  float* out = (float*)d_out;

  // ws layout (~29 MB): xh 13.6 MB | wh 6.8 MB | w2h 0.13 MB | part 8.4 MB
  u16* xh  = (u16*)d_ws;
  u16* wh  = xh + (size_t)BATCH * KP;
  u16* w2h = wh + (size_t)HID * KP;
  float* part = (float*)(w2h + 16 * HID);

  hipLaunchKernelGGL(prep_kernel, dim3(2048), dim3(256), 0, stream, x, W1, W2, xh, wh, w2h);
  hipLaunchKernelGGL(gemm_kernel, dim3(NCT, BATCH / BM), dim3(512), 0, stream,
                     xh, wh, w2h, b1, part);
  hipLaunchKernelGGL(reduce_kernel, dim3((BATCH * OUT_F + 255) / 256), dim3(256), 0, stream,
                     part, b2, out);
}